// Round 4
// baseline (96.741 us; speedup 1.0000x reference)
//
#include <hip/hip_runtime.h>

// Problem constants (from reference setup_inputs)
#define NROW 10000   // N*N
#define NN   100     // N
#define PP   12      // p
#define BB   128     // batch
#define RPB  8       // rows per block in f_kernel

typedef float f32x4 __attribute__((ext_vector_type(4)));

// ---------------------------------------------------------------------------
// Kernel 1: F[row] = sum_k g[row,k] * weights[k]^2
// 1250 blocks x 512 threads; each block owns 8 rows, one wave per row.
// w^2 staged in LDS once per block. g streamed with plain float4 loads
// (A/B vs round-3's nontemporal: testing whether nt capped read BW).
// Vector f32x4 accumulator: 4 independent FMAs per 16B, horizontal reduce
// once after the loop (round-3 did 8 dependent ops per 16B).
// ---------------------------------------------------------------------------
__global__ __launch_bounds__(512) void f_kernel(const float* __restrict__ g,
                                                const float* __restrict__ w,
                                                float* __restrict__ Fout) {
    __shared__ f32x4 ws4[NROW / 4];           // 40 KB of w^2
    const int tid = threadIdx.x;

    const f32x4* wv4 = (const f32x4*)w;
    for (int c = tid; c < NROW / 4; c += 512) {
        f32x4 v = wv4[c];
        ws4[c] = v * v;
    }
    __syncthreads();

    const int wave = tid >> 6;
    const int lane = tid & 63;
    const int row  = blockIdx.x * RPB + wave;

    const f32x4* grow = (const f32x4*)(g + (size_t)row * NROW);
    f32x4 acc4 = {0.f, 0.f, 0.f, 0.f};
    #pragma unroll 2
    for (int c = lane; c < NROW / 4; c += 64) {
        acc4 += grow[c] * ws4[c];             // 4 independent FMAs
    }
    float acc = acc4.x + acc4.y + acc4.z + acc4.w;
    #pragma unroll
    for (int off = 32; off > 0; off >>= 1) acc += __shfl_down(acc, off, 64);
    if (lane == 0) Fout[row] = acc;
}

// ---------------------------------------------------------------------------
// Kernel 2: Z[b,n] = sum_p sum_m softmax_m(-alpha[x_i[b,p]] * F[n,m]) * x[b,m,p]
// One 512-thread block per b. 4 lanes per output row n; lane q handles
// p in {3q..3q+2}; group-of-4 shfl_xor reduces. F staged in LDS stride 101.
// Softmax stabilized via per-row min of F (alpha > 0 => max(-a*F) = -a*minF).
// ---------------------------------------------------------------------------
__global__ __launch_bounds__(512) void z_kernel(const float* __restrict__ x,
                                                const float* __restrict__ alphas,
                                                const int*   __restrict__ xi,
                                                const float* __restrict__ F,
                                                float* __restrict__ Z) {
    const int b = blockIdx.x;
    __shared__ float Fs[NN * 101];
    __shared__ float xs[NN * PP];
    __shared__ float al[PP];
    const int tid = threadIdx.x;

    for (int j = tid; j < NROW; j += 512)
        Fs[(j / NN) * 101 + (j % NN)] = F[j];
    for (int j = tid; j < NN * PP; j += 512)
        xs[j] = x[(size_t)b * (NN * PP) + j];
    if (tid < PP) al[tid] = alphas[xi[b * PP + tid]];
    __syncthreads();

    const int n = tid >> 2;     // output row
    const int q = tid & 3;      // sub-lane within the row group
    if (n < NN) {
        const float* Fr = &Fs[n * 101];

        float rmin = Fr[q * 25];
        #pragma unroll
        for (int m = 1; m < 25; m++) rmin = fminf(rmin, Fr[q * 25 + m]);
        rmin = fminf(rmin, __shfl_xor(rmin, 1, 64));
        rmin = fminf(rmin, __shfl_xor(rmin, 2, 64));

        float zacc = 0.f;
        #pragma unroll
        for (int pp = 0; pp < 3; pp++) {
            const int p = q * 3 + pp;
            const float a = al[p];
            float num = 0.f, den = 0.f;
            for (int m = 0; m < NN; m++) {
                float e = __expf(a * (rmin - Fr[m]));   // exponent <= 0
                num += e * xs[m * PP + p];
                den += e;
            }
            zacc += num / den;
        }
        zacc += __shfl_xor(zacc, 1, 64);
        zacc += __shfl_xor(zacc, 2, 64);
        if (q == 0) Z[b * NN + n] = zacc;
    }
}

extern "C" void kernel_launch(void* const* d_in, const int* in_sizes, int n_in,
                              void* d_out, int out_size, void* d_ws, size_t ws_size,
                              hipStream_t stream) {
    const float* x      = (const float*)d_in[0];   // [128,100,12]
    const float* g      = (const float*)d_in[1];   // [10000,10000]
    const float* w      = (const float*)d_in[2];   // [10000,1]
    const float* alphas = (const float*)d_in[3];   // [4000,1]
    const int*   xi     = (const int*)d_in[4];     // [128,12]

    float* Z = (float*)d_out;            // [128,100] -> 12800 floats
    float* F = (float*)d_out + BB * NN;  // [10000]   -> next 10000 floats

    f_kernel<<<NROW / RPB, 512, 0, stream>>>(g, w, F);
    z_kernel<<<BB, 512, 0, stream>>>(x, alphas, xi, F, Z);
}

// Round 5
// 89.609 us; speedup vs baseline: 1.0796x; 1.0796x over previous
//
#include <hip/hip_runtime.h>

// Problem constants (from reference setup_inputs)
#define NROW 10000   // N*N
#define NN   100     // N
#define PP   12      // p
#define BB   128     // batch
#define RPB  8       // rows per block in f_kernel

typedef float f32x4 __attribute__((ext_vector_type(4)));

// ---------------------------------------------------------------------------
// Kernel 0: w2[k] = w[k]^2  (one-time, 40 KB into d_ws)
// ---------------------------------------------------------------------------
__global__ void w2_kernel(const float* __restrict__ w, float* __restrict__ w2) {
    int i = blockIdx.x * 256 + threadIdx.x;
    if (i < NROW) { float v = w[i]; w2[i] = v * v; }
}

// ---------------------------------------------------------------------------
// Kernel 1: F[row] = sum_k g[row,k] * w2[k]
// 1250 blocks x 512 threads, one wave per row, NO LDS / NO barrier:
// w2 read through L1 (40 KB, hot across all waves of the CU), g streamed
// with non-temporal float4 loads (keeps L2 clean for w2). Vector f32x4
// accumulator -> 4 independent FMAs per 16 B; wave-local butterfly reduce.
// ---------------------------------------------------------------------------
__global__ __launch_bounds__(512) void f_kernel(const float* __restrict__ g,
                                                const float* __restrict__ w2,
                                                float* __restrict__ Fout) {
    const int tid  = threadIdx.x;
    const int wave = tid >> 6;
    const int lane = tid & 63;
    const int row  = blockIdx.x * RPB + wave;

    const f32x4* grow = (const f32x4*)(g + (size_t)row * NROW);
    const f32x4* wv4  = (const f32x4*)w2;
    f32x4 acc4 = {0.f, 0.f, 0.f, 0.f};
    #pragma unroll 4
    for (int c = lane; c < NROW / 4; c += 64) {
        acc4 += __builtin_nontemporal_load(&grow[c]) * wv4[c];
    }
    float acc = acc4.x + acc4.y + acc4.z + acc4.w;
    #pragma unroll
    for (int off = 32; off > 0; off >>= 1) acc += __shfl_down(acc, off, 64);
    if (lane == 0) Fout[row] = acc;
}

// ---------------------------------------------------------------------------
// Kernel 2: Z[b,n] = sum_p sum_m softmax_m(-alpha[x_i[b,p]] * F[n,m]) * x[b,m,p]
// One 512-thread block per b. 4 lanes per output row n; lane q handles
// p in {3q..3q+2}; group-of-4 shfl_xor reduces. F staged in LDS stride 101.
// Softmax stabilized via per-row min of F (alpha > 0 => max(-a*F) = -a*minF).
// ---------------------------------------------------------------------------
__global__ __launch_bounds__(512) void z_kernel(const float* __restrict__ x,
                                                const float* __restrict__ alphas,
                                                const int*   __restrict__ xi,
                                                const float* __restrict__ F,
                                                float* __restrict__ Z) {
    const int b = blockIdx.x;
    __shared__ float Fs[NN * 101];
    __shared__ float xs[NN * PP];
    __shared__ float al[PP];
    const int tid = threadIdx.x;

    for (int j = tid; j < NROW; j += 512)
        Fs[(j / NN) * 101 + (j % NN)] = F[j];
    for (int j = tid; j < NN * PP; j += 512)
        xs[j] = x[(size_t)b * (NN * PP) + j];
    if (tid < PP) al[tid] = alphas[xi[b * PP + tid]];
    __syncthreads();

    const int n = tid >> 2;     // output row
    const int q = tid & 3;      // sub-lane within the row group
    if (n < NN) {
        const float* Fr = &Fs[n * 101];

        float rmin = Fr[q * 25];
        #pragma unroll
        for (int m = 1; m < 25; m++) rmin = fminf(rmin, Fr[q * 25 + m]);
        rmin = fminf(rmin, __shfl_xor(rmin, 1, 64));
        rmin = fminf(rmin, __shfl_xor(rmin, 2, 64));

        float zacc = 0.f;
        #pragma unroll
        for (int pp = 0; pp < 3; pp++) {
            const int p = q * 3 + pp;
            const float a = al[p];
            float num = 0.f, den = 0.f;
            for (int m = 0; m < NN; m++) {
                float e = __expf(a * (rmin - Fr[m]));   // exponent <= 0
                num += e * xs[m * PP + p];
                den += e;
            }
            zacc += num / den;
        }
        zacc += __shfl_xor(zacc, 1, 64);
        zacc += __shfl_xor(zacc, 2, 64);
        if (q == 0) Z[b * NN + n] = zacc;
    }
}

extern "C" void kernel_launch(void* const* d_in, const int* in_sizes, int n_in,
                              void* d_out, int out_size, void* d_ws, size_t ws_size,
                              hipStream_t stream) {
    const float* x      = (const float*)d_in[0];   // [128,100,12]
    const float* g      = (const float*)d_in[1];   // [10000,10000]
    const float* w      = (const float*)d_in[2];   // [10000,1]
    const float* alphas = (const float*)d_in[3];   // [4000,1]
    const int*   xi     = (const int*)d_in[4];     // [128,12]

    float* Z  = (float*)d_out;            // [128,100] -> 12800 floats
    float* F  = (float*)d_out + BB * NN;  // [10000]   -> next 10000 floats
    float* w2 = (float*)d_ws;             // 40 KB scratch

    w2_kernel<<<(NROW + 255) / 256, 256, 0, stream>>>(w, w2);
    f_kernel<<<NROW / RPB, 512, 0, stream>>>(g, w2, F);
    z_kernel<<<BB, 512, 0, stream>>>(x, alphas, xi, F, Z);
}